// Round 2
// baseline (3199.193 us; speedup 1.0000x reference)
//
#include <hip/hip_runtime.h>
#include <math.h>

#define N_NODES 100000
#define E_EDGES 1600000
#define HALF_E  (E_EDGES / 2)

// ---------------- h = x @ w_in + b_in   (N x 128 -> N x 64) ----------------
// thread-per-row: acc[64] in VGPRs, stream x via float4, weights via s_load.
__global__ __launch_bounds__(256, 2) void k_lin_in(const float* __restrict__ x,
                                                   const float* __restrict__ w,
                                                   const float* __restrict__ b,
                                                   float* __restrict__ h) {
    int r = blockIdx.x * 256 + threadIdx.x;
    if (r >= N_NODES) return;
    float acc[64];
#pragma unroll
    for (int j = 0; j < 64; ++j) acc[j] = b[j];
    const float4* xv = (const float4*)(x + (size_t)r * 128);
    for (int k4 = 0; k4 < 32; ++k4) {
        float4 v = xv[k4];
#pragma unroll
        for (int kk = 0; kk < 4; ++kk) {
            float xk = (&v.x)[kk];
            const float* wrow = w + (k4 * 4 + kk) * 64;
#pragma unroll
            for (int j = 0; j < 64; ++j) acc[j] = fmaf(xk, wrow[j], acc[j]);
        }
    }
    float4* hv = (float4*)(h + (size_t)r * 64);
#pragma unroll
    for (int j4 = 0; j4 < 16; ++j4)
        hv[j4] = make_float4(acc[4 * j4], acc[4 * j4 + 1], acc[4 * j4 + 2], acc[4 * j4 + 3]);
}

// ---------------- msg = relu(relu(h@m1+b1)@m2+b2)  per NODE ----------------
__global__ __launch_bounds__(256, 2) void k_msg(const float* __restrict__ h,
                                                const float* __restrict__ w1,
                                                const float* __restrict__ b1,
                                                const float* __restrict__ w2,
                                                const float* __restrict__ b2,
                                                float* __restrict__ msg) {
    int r = blockIdx.x * 256 + threadIdx.x;
    if (r >= N_NODES) return;
    float t[64];
#pragma unroll
    for (int j = 0; j < 64; ++j) t[j] = b1[j];
    const float4* hv = (const float4*)(h + (size_t)r * 64);
    for (int k4 = 0; k4 < 16; ++k4) {
        float4 v = hv[k4];
#pragma unroll
        for (int kk = 0; kk < 4; ++kk) {
            float xk = (&v.x)[kk];
            const float* wrow = w1 + (k4 * 4 + kk) * 64;
#pragma unroll
            for (int j = 0; j < 64; ++j) t[j] = fmaf(xk, wrow[j], t[j]);
        }
    }
#pragma unroll
    for (int j = 0; j < 64; ++j) t[j] = fmaxf(t[j], 0.0f);
    // phase 2, chunks of 16 outputs
    for (int c = 0; c < 4; ++c) {
        float o[16];
#pragma unroll
        for (int j = 0; j < 16; ++j) o[j] = b2[c * 16 + j];
#pragma unroll
        for (int k = 0; k < 64; ++k) {
            const float* wrow = w2 + k * 64 + c * 16;
#pragma unroll
            for (int j = 0; j < 16; ++j) o[j] = fmaf(t[k], wrow[j], o[j]);
        }
        float4* mv = (float4*)(msg + (size_t)r * 64 + c * 16);
#pragma unroll
        for (int j4 = 0; j4 < 4; ++j4)
            mv[j4] = make_float4(fmaxf(o[4 * j4], 0.0f), fmaxf(o[4 * j4 + 1], 0.0f),
                                 fmaxf(o[4 * j4 + 2], 0.0f), fmaxf(o[4 * j4 + 3], 0.0f));
    }
}

// ---------------- deg[row[e]] += 1 ----------------
__global__ __launch_bounds__(256) void k_deg(const int* __restrict__ rowIdx,
                                             float* __restrict__ deg) {
    for (int e = blockIdx.x * 256 + threadIdx.x; e < E_EDGES; e += gridDim.x * 256)
        atomicAdd(&deg[rowIdx[e]], 1.0f);
}

// ---------------- agg[row[e]] += msg[col[e]]  (16 lanes per edge) ----------------
__global__ __launch_bounds__(256) void k_scatter(const int* __restrict__ rowIdx,
                                                 const int* __restrict__ colIdx,
                                                 const float* __restrict__ msg,
                                                 float* __restrict__ agg) {
    const int lane = threadIdx.x & 63;
    const int sub = lane & 15;          // 0..15 : which float4 of the row
    const int grp = lane >> 4;          // 0..3  : which edge within the wave
    const int waveId = (blockIdx.x * 256 + threadIdx.x) >> 6;
    const int step = gridDim.x * 4 * 4; // waves * 4 edges each
    for (int e = waveId * 4 + grp; e < E_EDGES; e += step) {
        int r = rowIdx[e];
        int c = colIdx[e];
        float4 v = *(const float4*)(msg + (size_t)c * 64 + sub * 4);
        float* dst = agg + (size_t)r * 64 + sub * 4;
        atomicAdd(dst + 0, v.x);
        atomicAdd(dst + 1, v.y);
        atomicAdd(dst + 2, v.z);
        atomicAdd(dst + 3, v.w);
    }
}

// ------- h += relu(concat(h, agg/clip(deg,1)) @ u1 + b1) @ u2 + b2 ----------
__global__ __launch_bounds__(256, 2) void k_update(float* __restrict__ h,
                                                   const float* __restrict__ agg,
                                                   const float* __restrict__ deg,
                                                   const float* __restrict__ u1,
                                                   const float* __restrict__ b1,
                                                   const float* __restrict__ u2,
                                                   const float* __restrict__ b2) {
    int r = blockIdx.x * 256 + threadIdx.x;
    if (r >= N_NODES) return;
    float t[64];
#pragma unroll
    for (int j = 0; j < 64; ++j) t[j] = b1[j];
    const float4* hv = (const float4*)(h + (size_t)r * 64);
    for (int k4 = 0; k4 < 16; ++k4) {
        float4 v = hv[k4];
#pragma unroll
        for (int kk = 0; kk < 4; ++kk) {
            float xk = (&v.x)[kk];
            const float* wrow = u1 + (k4 * 4 + kk) * 64;
#pragma unroll
            for (int j = 0; j < 64; ++j) t[j] = fmaf(xk, wrow[j], t[j]);
        }
    }
    float dv = deg[r];
    float inv = 1.0f / fmaxf(dv, 1.0f);
    const float4* av4 = (const float4*)(agg + (size_t)r * 64);
    for (int k4 = 0; k4 < 16; ++k4) {
        float4 v = av4[k4];
#pragma unroll
        for (int kk = 0; kk < 4; ++kk) {
            float xk = (&v.x)[kk] * inv;
            const float* wrow = u1 + (64 + k4 * 4 + kk) * 64;
#pragma unroll
            for (int j = 0; j < 64; ++j) t[j] = fmaf(xk, wrow[j], t[j]);
        }
    }
#pragma unroll
    for (int j = 0; j < 64; ++j) t[j] = fmaxf(t[j], 0.0f);
    for (int c = 0; c < 4; ++c) {
        float o[16];
#pragma unroll
        for (int j = 0; j < 16; ++j) o[j] = b2[c * 16 + j];
#pragma unroll
        for (int k = 0; k < 64; ++k) {
            const float* wrow = u2 + k * 64 + c * 16;
#pragma unroll
            for (int j = 0; j < 16; ++j) o[j] = fmaf(t[k], wrow[j], o[j]);
        }
        float4* hw = (float4*)(h + (size_t)r * 64 + c * 16);
#pragma unroll
        for (int j4 = 0; j4 < 4; ++j4) {
            float4 old = hw[j4];
            hw[j4] = make_float4(old.x + o[4 * j4], old.y + o[4 * j4 + 1],
                                 old.z + o[4 * j4 + 2], old.w + o[4 * j4 + 3]);
        }
    }
}

// ------- hA[v] = h[v]@h1w[0:64]   + deg[v]*h1w[128] + h1b
//         hB[v] = h[v]@h1w[64:128] + deg[v]*h1w[129] -------
__global__ __launch_bounds__(256, 2) void k_headpre(const float* __restrict__ h,
                                                    const float* __restrict__ deg,
                                                    const float* __restrict__ w,
                                                    const float* __restrict__ b,
                                                    float* __restrict__ hA,
                                                    float* __restrict__ hB) {
    int r = blockIdx.x * 256 + threadIdx.x;
    if (r >= N_NODES) return;
    float dv = deg[r];
    const float4* hv = (const float4*)(h + (size_t)r * 64);
    // pass A
    {
        float acc[64];
#pragma unroll
        for (int j = 0; j < 64; ++j) acc[j] = b[j] + dv * w[128 * 64 + j];
        for (int k4 = 0; k4 < 16; ++k4) {
            float4 v = hv[k4];
#pragma unroll
            for (int kk = 0; kk < 4; ++kk) {
                float xk = (&v.x)[kk];
                const float* wrow = w + (k4 * 4 + kk) * 64;
#pragma unroll
                for (int j = 0; j < 64; ++j) acc[j] = fmaf(xk, wrow[j], acc[j]);
            }
        }
        float4* ov = (float4*)(hA + (size_t)r * 64);
#pragma unroll
        for (int j4 = 0; j4 < 16; ++j4)
            ov[j4] = make_float4(acc[4 * j4], acc[4 * j4 + 1], acc[4 * j4 + 2], acc[4 * j4 + 3]);
    }
    // pass B
    {
        float acc[64];
#pragma unroll
        for (int j = 0; j < 64; ++j) acc[j] = dv * w[129 * 64 + j];
        for (int k4 = 0; k4 < 16; ++k4) {
            float4 v = hv[k4];
#pragma unroll
            for (int kk = 0; kk < 4; ++kk) {
                float xk = (&v.x)[kk];
                const float* wrow = w + (64 + k4 * 4 + kk) * 64;
#pragma unroll
                for (int j = 0; j < 64; ++j) acc[j] = fmaf(xk, wrow[j], acc[j]);
            }
        }
        float4* ov = (float4*)(hB + (size_t)r * 64);
#pragma unroll
        for (int j4 = 0; j4 < 16; ++j4)
            ov[j4] = make_float4(acc[4 * j4], acc[4 * j4 + 1], acc[4 * j4 + 2], acc[4 * j4 + 3]);
    }
}

// ------- out[e] = out[e+HALF] = softplus(relu(hA[src]+hB[dst]) . h2w + h2b) + 1e-6 ------
// 16 lanes per edge, float4 gathers.
__global__ __launch_bounds__(256) void k_head(const int* __restrict__ rowIdx,
                                              const int* __restrict__ colIdx,
                                              const float* __restrict__ hA,
                                              const float* __restrict__ hB,
                                              const float* __restrict__ w2,
                                              const float* __restrict__ b2,
                                              float* __restrict__ out) {
    const int lane = threadIdx.x & 63;
    const int sub = lane & 15;
    const int grp = lane >> 4;
    const int waveId = (blockIdx.x * 256 + threadIdx.x) >> 6;
    const int step = gridDim.x * 4 * 4;
    const float4 wv = *(const float4*)(w2 + sub * 4);
    const float b2v = b2[0];
    for (int e = waveId * 4 + grp; e < HALF_E; e += step) {
        int s = rowIdx[e];
        int d = colIdx[e];
        float4 a = *(const float4*)(hA + (size_t)s * 64 + sub * 4);
        float4 bb = *(const float4*)(hB + (size_t)d * 64 + sub * 4);
        float t0 = fmaxf(a.x + bb.x, 0.0f);
        float t1 = fmaxf(a.y + bb.y, 0.0f);
        float t2 = fmaxf(a.z + bb.z, 0.0f);
        float t3 = fmaxf(a.w + bb.w, 0.0f);
        float p = t0 * wv.x + t1 * wv.y + t2 * wv.z + t3 * wv.w;
        p += __shfl_xor(p, 1);
        p += __shfl_xor(p, 2);
        p += __shfl_xor(p, 4);
        p += __shfl_xor(p, 8);
        if (sub == 0) {
            float sv = p + b2v;
            float sp = fmaxf(sv, 0.0f) + log1pf(expf(-fabsf(sv)));
            float wvv = sp + 1e-6f;
            out[e] = wvv;
            out[e + HALF_E] = wvv;
        }
    }
}

extern "C" void kernel_launch(void* const* d_in, const int* in_sizes, int n_in,
                              void* d_out, int out_size, void* d_ws, size_t ws_size,
                              hipStream_t stream) {
    const float* x      = (const float*)d_in[0];
    const int*   rowIdx = (const int*)d_in[1];
    const int*   colIdx = rowIdx + E_EDGES;
    const float* w_in   = (const float*)d_in[2];
    const float* b_in   = (const float*)d_in[3];
    const float* l0_m1w = (const float*)d_in[4];
    const float* l0_m1b = (const float*)d_in[5];
    const float* l0_m2w = (const float*)d_in[6];
    const float* l0_m2b = (const float*)d_in[7];
    const float* l0_u1w = (const float*)d_in[8];
    const float* l0_u1b = (const float*)d_in[9];
    const float* l0_u2w = (const float*)d_in[10];
    const float* l0_u2b = (const float*)d_in[11];
    const float* l1_m1w = (const float*)d_in[12];
    const float* l1_m1b = (const float*)d_in[13];
    const float* l1_m2w = (const float*)d_in[14];
    const float* l1_m2b = (const float*)d_in[15];
    const float* l1_u1w = (const float*)d_in[16];
    const float* l1_u1b = (const float*)d_in[17];
    const float* l1_u2w = (const float*)d_in[18];
    const float* l1_u2b = (const float*)d_in[19];
    const float* h1w    = (const float*)d_in[20];
    const float* h1b    = (const float*)d_in[21];
    const float* h2w    = (const float*)d_in[22];
    const float* h2b    = (const float*)d_in[23];

    float* out = (float*)d_out;

    float* h   = (float*)d_ws;                    // N x 64
    float* msg = h   + (size_t)N_NODES * 64;      // N x 64  (later hA)
    float* agg = msg + (size_t)N_NODES * 64;      // N x 64  (later hB)
    float* deg = agg + (size_t)N_NODES * 64;      // N

    const int nodeBlocks = (N_NODES + 255) / 256;

    hipMemsetAsync(deg, 0, (size_t)N_NODES * sizeof(float), stream);
    hipMemsetAsync(agg, 0, (size_t)N_NODES * 64 * sizeof(float), stream);

    k_deg<<<2048, 256, 0, stream>>>(rowIdx, deg);
    k_lin_in<<<nodeBlocks, 256, 0, stream>>>(x, w_in, b_in, h);

    // ---- layer 0 ----
    k_msg<<<nodeBlocks, 256, 0, stream>>>(h, l0_m1w, l0_m1b, l0_m2w, l0_m2b, msg);
    k_scatter<<<8192, 256, 0, stream>>>(rowIdx, colIdx, msg, agg);
    k_update<<<nodeBlocks, 256, 0, stream>>>(h, agg, deg, l0_u1w, l0_u1b, l0_u2w, l0_u2b);

    hipMemsetAsync(agg, 0, (size_t)N_NODES * 64 * sizeof(float), stream);

    // ---- layer 1 ----
    k_msg<<<nodeBlocks, 256, 0, stream>>>(h, l1_m1w, l1_m1b, l1_m2w, l1_m2b, msg);
    k_scatter<<<8192, 256, 0, stream>>>(rowIdx, colIdx, msg, agg);
    k_update<<<nodeBlocks, 256, 0, stream>>>(h, agg, deg, l1_u1w, l1_u1b, l1_u2w, l1_u2b);

    // ---- head ----
    k_headpre<<<nodeBlocks, 256, 0, stream>>>(h, deg, h1w, h1b, msg /*hA*/, agg /*hB*/);
    k_head<<<4096, 256, 0, stream>>>(rowIdx, colIdx, msg, agg, h2w, h2b, out);
}

// Round 3
// 764.395 us; speedup vs baseline: 4.1853x; 4.1853x over previous
//
#include <hip/hip_runtime.h>
#include <math.h>

#define N_NODES 100000
#define E_EDGES 1600000
#define HALF_E  (E_EDGES / 2)

// ============ CSR build ============

// cnt[row[e]]++  (int atomics, 64x fewer than the old float scatter)
__global__ __launch_bounds__(256) void k_hist(const int* __restrict__ rowIdx,
                                              int* __restrict__ cnt) {
    int e = blockIdx.x * 256 + threadIdx.x;
    if (e < E_EDGES) atomicAdd(&cnt[rowIdx[e]], 1);
}

// exclusive prefix sum of cnt -> start   (single block, 1024 thr, 4 elems/thr)
__global__ __launch_bounds__(1024) void k_scan(const int* __restrict__ cnt,
                                               int* __restrict__ start) {
    __shared__ int buf[1024];
    const int tid = threadIdx.x;
    int offset = 0;
    for (int base = 0; base < N_NODES; base += 4096) {
        int i0 = base + tid * 4;
        int v0 = (i0 + 0 < N_NODES) ? cnt[i0 + 0] : 0;
        int v1 = (i0 + 1 < N_NODES) ? cnt[i0 + 1] : 0;
        int v2 = (i0 + 2 < N_NODES) ? cnt[i0 + 2] : 0;
        int v3 = (i0 + 3 < N_NODES) ? cnt[i0 + 3] : 0;
        int s = v0 + v1 + v2 + v3;
        buf[tid] = s;
        __syncthreads();
        for (int st = 1; st < 1024; st <<= 1) {
            int t = (tid >= st) ? buf[tid - st] : 0;
            __syncthreads();
            buf[tid] += t;
            __syncthreads();
        }
        int excl = buf[tid] - s;
        int total = buf[1023];
        int run = offset + excl;
        if (i0 + 0 < N_NODES) { start[i0 + 0] = run; run += v0; }
        if (i0 + 1 < N_NODES) { start[i0 + 1] = run; run += v1; }
        if (i0 + 2 < N_NODES) { start[i0 + 2] = run; run += v2; }
        if (i0 + 3 < N_NODES) { start[i0 + 3] = run; run += v3; }
        __syncthreads();
        offset += total;
    }
}

// csr[atomicAdd(&start[row[e]],1)] = col[e].  Afterwards start[r] == end(r),
// and begin(r) == (r ? start[r-1] : 0)  -- no cursor array needed.
__global__ __launch_bounds__(256) void k_fill(const int* __restrict__ rowIdx,
                                              const int* __restrict__ colIdx,
                                              int* __restrict__ start,
                                              int* __restrict__ csr) {
    int e = blockIdx.x * 256 + threadIdx.x;
    if (e < E_EDGES) {
        int r = rowIdx[e];
        int pos = atomicAdd(&start[r], 1);
        csr[pos] = colIdx[e];
    }
}

// ============ node MLPs (thread-per-row, regs) ============

__global__ __launch_bounds__(256, 2) void k_lin_in(const float* __restrict__ x,
                                                   const float* __restrict__ w,
                                                   const float* __restrict__ b,
                                                   float* __restrict__ h) {
    int r = blockIdx.x * 256 + threadIdx.x;
    if (r >= N_NODES) return;
    float acc[64];
#pragma unroll
    for (int j = 0; j < 64; ++j) acc[j] = b[j];
    const float4* xv = (const float4*)(x + (size_t)r * 128);
    for (int k4 = 0; k4 < 32; ++k4) {
        float4 v = xv[k4];
#pragma unroll
        for (int kk = 0; kk < 4; ++kk) {
            float xk = (&v.x)[kk];
            const float* wrow = w + (k4 * 4 + kk) * 64;
#pragma unroll
            for (int j = 0; j < 64; ++j) acc[j] = fmaf(xk, wrow[j], acc[j]);
        }
    }
    float4* hv = (float4*)(h + (size_t)r * 64);
#pragma unroll
    for (int j4 = 0; j4 < 16; ++j4)
        hv[j4] = make_float4(acc[4 * j4], acc[4 * j4 + 1], acc[4 * j4 + 2], acc[4 * j4 + 3]);
}

__global__ __launch_bounds__(256, 2) void k_msg(const float* __restrict__ h,
                                                const float* __restrict__ w1,
                                                const float* __restrict__ b1,
                                                const float* __restrict__ w2,
                                                const float* __restrict__ b2,
                                                float* __restrict__ msg) {
    int r = blockIdx.x * 256 + threadIdx.x;
    if (r >= N_NODES) return;
    float t[64];
#pragma unroll
    for (int j = 0; j < 64; ++j) t[j] = b1[j];
    const float4* hv = (const float4*)(h + (size_t)r * 64);
    for (int k4 = 0; k4 < 16; ++k4) {
        float4 v = hv[k4];
#pragma unroll
        for (int kk = 0; kk < 4; ++kk) {
            float xk = (&v.x)[kk];
            const float* wrow = w1 + (k4 * 4 + kk) * 64;
#pragma unroll
            for (int j = 0; j < 64; ++j) t[j] = fmaf(xk, wrow[j], t[j]);
        }
    }
#pragma unroll
    for (int j = 0; j < 64; ++j) t[j] = fmaxf(t[j], 0.0f);
    for (int c = 0; c < 4; ++c) {
        float o[16];
#pragma unroll
        for (int j = 0; j < 16; ++j) o[j] = b2[c * 16 + j];
#pragma unroll
        for (int k = 0; k < 64; ++k) {
            const float* wrow = w2 + k * 64 + c * 16;
#pragma unroll
            for (int j = 0; j < 16; ++j) o[j] = fmaf(t[k], wrow[j], o[j]);
        }
        float4* mv = (float4*)(msg + (size_t)r * 64 + c * 16);
#pragma unroll
        for (int j4 = 0; j4 < 4; ++j4)
            mv[j4] = make_float4(fmaxf(o[4 * j4], 0.0f), fmaxf(o[4 * j4 + 1], 0.0f),
                                 fmaxf(o[4 * j4 + 2], 0.0f), fmaxf(o[4 * j4 + 3], 0.0f));
    }
}

// ============ aggregation: gather (wave per node, no atomics) ============
__global__ __launch_bounds__(256) void k_gather(const int* __restrict__ start,
                                                const int* __restrict__ csr,
                                                const float* __restrict__ msg,
                                                float* __restrict__ agg) {
    const int lane = threadIdx.x & 63;
    const int wid  = threadIdx.x >> 6;
    int r = blockIdx.x * 4 + wid;
    if (r >= N_NODES) return;
    int b = (r == 0) ? 0 : start[r - 1];
    int e0 = start[r];
    float acc0 = 0.0f, acc1 = 0.0f;
    for (int base = b; base < e0; base += 64) {
        int n = e0 - base;
        if (n > 64) n = 64;
        int c = 0;
        if (base + lane < e0) c = csr[base + lane];
        int j = 0;
        for (; j + 4 <= n; j += 4) {
            int c0 = __shfl(c, j, 64);
            int c1 = __shfl(c, j + 1, 64);
            int c2 = __shfl(c, j + 2, 64);
            int c3 = __shfl(c, j + 3, 64);
            float l0 = msg[(size_t)c0 * 64 + lane];
            float l1 = msg[(size_t)c1 * 64 + lane];
            float l2 = msg[(size_t)c2 * 64 + lane];
            float l3 = msg[(size_t)c3 * 64 + lane];
            acc0 += l0 + l2;
            acc1 += l1 + l3;
        }
        for (; j < n; ++j) {
            int cj = __shfl(c, j, 64);
            acc0 += msg[(size_t)cj * 64 + lane];
        }
    }
    agg[(size_t)r * 64 + lane] = acc0 + acc1;
}

// ------- h += relu(concat(h, agg/clip(deg,1)) @ u1 + b1) @ u2 + b2 ----------
__global__ __launch_bounds__(256, 2) void k_update(float* __restrict__ h,
                                                   const float* __restrict__ agg,
                                                   const int* __restrict__ cnt,
                                                   const float* __restrict__ u1,
                                                   const float* __restrict__ b1,
                                                   const float* __restrict__ u2,
                                                   const float* __restrict__ b2) {
    int r = blockIdx.x * 256 + threadIdx.x;
    if (r >= N_NODES) return;
    float t[64];
#pragma unroll
    for (int j = 0; j < 64; ++j) t[j] = b1[j];
    const float4* hv = (const float4*)(h + (size_t)r * 64);
    for (int k4 = 0; k4 < 16; ++k4) {
        float4 v = hv[k4];
#pragma unroll
        for (int kk = 0; kk < 4; ++kk) {
            float xk = (&v.x)[kk];
            const float* wrow = u1 + (k4 * 4 + kk) * 64;
#pragma unroll
            for (int j = 0; j < 64; ++j) t[j] = fmaf(xk, wrow[j], t[j]);
        }
    }
    float dv = (float)cnt[r];
    float inv = 1.0f / fmaxf(dv, 1.0f);
    const float4* av4 = (const float4*)(agg + (size_t)r * 64);
    for (int k4 = 0; k4 < 16; ++k4) {
        float4 v = av4[k4];
#pragma unroll
        for (int kk = 0; kk < 4; ++kk) {
            float xk = (&v.x)[kk] * inv;
            const float* wrow = u1 + (64 + k4 * 4 + kk) * 64;
#pragma unroll
            for (int j = 0; j < 64; ++j) t[j] = fmaf(xk, wrow[j], t[j]);
        }
    }
#pragma unroll
    for (int j = 0; j < 64; ++j) t[j] = fmaxf(t[j], 0.0f);
    for (int c = 0; c < 4; ++c) {
        float o[16];
#pragma unroll
        for (int j = 0; j < 16; ++j) o[j] = b2[c * 16 + j];
#pragma unroll
        for (int k = 0; k < 64; ++k) {
            const float* wrow = u2 + k * 64 + c * 16;
#pragma unroll
            for (int j = 0; j < 16; ++j) o[j] = fmaf(t[k], wrow[j], o[j]);
        }
        float4* hw = (float4*)(h + (size_t)r * 64 + c * 16);
#pragma unroll
        for (int j4 = 0; j4 < 4; ++j4) {
            float4 old = hw[j4];
            hw[j4] = make_float4(old.x + o[4 * j4], old.y + o[4 * j4 + 1],
                                 old.z + o[4 * j4 + 2], old.w + o[4 * j4 + 3]);
        }
    }
}

// ------- hA[v] = h[v]@h1w[0:64]   + deg[v]*h1w[128] + h1b
//         hB[v] = h[v]@h1w[64:128] + deg[v]*h1w[129] -------
__global__ __launch_bounds__(256, 2) void k_headpre(const float* __restrict__ h,
                                                    const int* __restrict__ cnt,
                                                    const float* __restrict__ w,
                                                    const float* __restrict__ b,
                                                    float* __restrict__ hA,
                                                    float* __restrict__ hB) {
    int r = blockIdx.x * 256 + threadIdx.x;
    if (r >= N_NODES) return;
    float dv = (float)cnt[r];
    const float4* hv = (const float4*)(h + (size_t)r * 64);
    {
        float acc[64];
#pragma unroll
        for (int j = 0; j < 64; ++j) acc[j] = b[j] + dv * w[128 * 64 + j];
        for (int k4 = 0; k4 < 16; ++k4) {
            float4 v = hv[k4];
#pragma unroll
            for (int kk = 0; kk < 4; ++kk) {
                float xk = (&v.x)[kk];
                const float* wrow = w + (k4 * 4 + kk) * 64;
#pragma unroll
                for (int j = 0; j < 64; ++j) acc[j] = fmaf(xk, wrow[j], acc[j]);
            }
        }
        float4* ov = (float4*)(hA + (size_t)r * 64);
#pragma unroll
        for (int j4 = 0; j4 < 16; ++j4)
            ov[j4] = make_float4(acc[4 * j4], acc[4 * j4 + 1], acc[4 * j4 + 2], acc[4 * j4 + 3]);
    }
    {
        float acc[64];
#pragma unroll
        for (int j = 0; j < 64; ++j) acc[j] = dv * w[129 * 64 + j];
        for (int k4 = 0; k4 < 16; ++k4) {
            float4 v = hv[k4];
#pragma unroll
            for (int kk = 0; kk < 4; ++kk) {
                float xk = (&v.x)[kk];
                const float* wrow = w + (64 + k4 * 4 + kk) * 64;
#pragma unroll
                for (int j = 0; j < 64; ++j) acc[j] = fmaf(xk, wrow[j], acc[j]);
            }
        }
        float4* ov = (float4*)(hB + (size_t)r * 64);
#pragma unroll
        for (int j4 = 0; j4 < 16; ++j4)
            ov[j4] = make_float4(acc[4 * j4], acc[4 * j4 + 1], acc[4 * j4 + 2], acc[4 * j4 + 3]);
    }
}

// ------- out[e] = out[e+HALF] = softplus(relu(hA[src]+hB[dst]) . h2w + h2b) + 1e-6 ------
__global__ __launch_bounds__(256) void k_head(const int* __restrict__ rowIdx,
                                              const int* __restrict__ colIdx,
                                              const float* __restrict__ hA,
                                              const float* __restrict__ hB,
                                              const float* __restrict__ w2,
                                              const float* __restrict__ b2,
                                              float* __restrict__ out) {
    const int lane = threadIdx.x & 63;
    const int sub = lane & 15;
    const int grp = lane >> 4;
    const int waveId = (blockIdx.x * 256 + threadIdx.x) >> 6;
    const int step = gridDim.x * 4 * 4;
    const float4 wv = *(const float4*)(w2 + sub * 4);
    const float b2v = b2[0];
    for (int e = waveId * 4 + grp; e < HALF_E; e += step) {
        int s = rowIdx[e];
        int d = colIdx[e];
        float4 a = *(const float4*)(hA + (size_t)s * 64 + sub * 4);
        float4 bb = *(const float4*)(hB + (size_t)d * 64 + sub * 4);
        float t0 = fmaxf(a.x + bb.x, 0.0f);
        float t1 = fmaxf(a.y + bb.y, 0.0f);
        float t2 = fmaxf(a.z + bb.z, 0.0f);
        float t3 = fmaxf(a.w + bb.w, 0.0f);
        float p = t0 * wv.x + t1 * wv.y + t2 * wv.z + t3 * wv.w;
        p += __shfl_xor(p, 1);
        p += __shfl_xor(p, 2);
        p += __shfl_xor(p, 4);
        p += __shfl_xor(p, 8);
        if (sub == 0) {
            float sv = p + b2v;
            float sp = fmaxf(sv, 0.0f) + log1pf(expf(-fabsf(sv)));
            float wvv = sp + 1e-6f;
            out[e] = wvv;
            out[e + HALF_E] = wvv;
        }
    }
}

extern "C" void kernel_launch(void* const* d_in, const int* in_sizes, int n_in,
                              void* d_out, int out_size, void* d_ws, size_t ws_size,
                              hipStream_t stream) {
    const float* x      = (const float*)d_in[0];
    const int*   rowIdx = (const int*)d_in[1];
    const int*   colIdx = rowIdx + E_EDGES;
    const float* w_in   = (const float*)d_in[2];
    const float* b_in   = (const float*)d_in[3];
    const float* l0_m1w = (const float*)d_in[4];
    const float* l0_m1b = (const float*)d_in[5];
    const float* l0_m2w = (const float*)d_in[6];
    const float* l0_m2b = (const float*)d_in[7];
    const float* l0_u1w = (const float*)d_in[8];
    const float* l0_u1b = (const float*)d_in[9];
    const float* l0_u2w = (const float*)d_in[10];
    const float* l0_u2b = (const float*)d_in[11];
    const float* l1_m1w = (const float*)d_in[12];
    const float* l1_m1b = (const float*)d_in[13];
    const float* l1_m2w = (const float*)d_in[14];
    const float* l1_m2b = (const float*)d_in[15];
    const float* l1_u1w = (const float*)d_in[16];
    const float* l1_u1b = (const float*)d_in[17];
    const float* l1_u2w = (const float*)d_in[18];
    const float* l1_u2b = (const float*)d_in[19];
    const float* h1w    = (const float*)d_in[20];
    const float* h1b    = (const float*)d_in[21];
    const float* h2w    = (const float*)d_in[22];
    const float* h2b    = (const float*)d_in[23];

    float* out = (float*)d_out;

    float* h     = (float*)d_ws;                  // N x 64
    float* msg   = h   + (size_t)N_NODES * 64;    // N x 64  (later hA)
    float* agg   = msg + (size_t)N_NODES * 64;    // N x 64  (later hB)
    int*   cnt   = (int*)(agg + (size_t)N_NODES * 64); // N (degree)
    int*   startA= cnt + N_NODES;                 // N (begin->end offsets)
    int*   csr   = startA + N_NODES;              // E (col sorted by row)

    const int nodeBlocks = (N_NODES + 255) / 256;
    const int edgeBlocks = (E_EDGES + 255) / 256;
    const int gatherBlocks = (N_NODES + 3) / 4;

    // ---- CSR build ----
    hipMemsetAsync(cnt, 0, (size_t)N_NODES * sizeof(int), stream);
    k_hist<<<edgeBlocks, 256, 0, stream>>>(rowIdx, cnt);
    k_scan<<<1, 1024, 0, stream>>>(cnt, startA);
    k_fill<<<edgeBlocks, 256, 0, stream>>>(rowIdx, colIdx, startA, csr);

    k_lin_in<<<nodeBlocks, 256, 0, stream>>>(x, w_in, b_in, h);

    // ---- layer 0 ----
    k_msg<<<nodeBlocks, 256, 0, stream>>>(h, l0_m1w, l0_m1b, l0_m2w, l0_m2b, msg);
    k_gather<<<gatherBlocks, 256, 0, stream>>>(startA, csr, msg, agg);
    k_update<<<nodeBlocks, 256, 0, stream>>>(h, agg, cnt, l0_u1w, l0_u1b, l0_u2w, l0_u2b);

    // ---- layer 1 ----
    k_msg<<<nodeBlocks, 256, 0, stream>>>(h, l1_m1w, l1_m1b, l1_m2w, l1_m2b, msg);
    k_gather<<<gatherBlocks, 256, 0, stream>>>(startA, csr, msg, agg);
    k_update<<<nodeBlocks, 256, 0, stream>>>(h, agg, cnt, l1_u1w, l1_u1b, l1_u2w, l1_u2b);

    // ---- head ----
    k_headpre<<<nodeBlocks, 256, 0, stream>>>(h, cnt, h1w, h1b, msg /*hA*/, agg /*hB*/);
    k_head<<<4096, 256, 0, stream>>>(rowIdx, colIdx, msg, agg, h2w, h2b, out);
}

// Round 4
// 698.652 us; speedup vs baseline: 4.5791x; 1.0941x over previous
//
#include <hip/hip_runtime.h>
#include <math.h>

#define N_NODES 100000
#define E_EDGES 1600000
#define HALF_E  (E_EDGES / 2)
#define SCAN_CHUNK 4096
#define NB_SCAN ((N_NODES + SCAN_CHUNK - 1) / SCAN_CHUNK)

typedef unsigned short ushort_t;

// ---- bf16 helpers (RNE pack, cheap unpack) ----
__device__ __forceinline__ unsigned bf16_1(float f) {
    unsigned u = __float_as_uint(f);
    return (u + 0x7fffu + ((u >> 16) & 1u)) >> 16;
}
__device__ __forceinline__ unsigned bf16_2(float a, float b) {
    return bf16_1(a) | (bf16_1(b) << 16);
}
__device__ __forceinline__ float bf16_f(ushort_t us) {
    return __uint_as_float(((unsigned)us) << 16);
}

// ============ CSR build ============

__global__ __launch_bounds__(256) void k_hist(const int* __restrict__ rowIdx,
                                              int* __restrict__ cnt) {
    int e = blockIdx.x * 256 + threadIdx.x;
    if (e < E_EDGES) atomicAdd(&cnt[rowIdx[e]], 1);
}

// per-block sums of cnt (blocks of SCAN_CHUNK)
__global__ __launch_bounds__(256) void k_bsum(const int* __restrict__ cnt,
                                              int* __restrict__ bsum) {
    __shared__ int lds[256];
    const int tid = threadIdx.x;
    int base = blockIdx.x * SCAN_CHUNK + tid * 16;
    int s = 0;
#pragma unroll
    for (int i = 0; i < 16; ++i) {
        int idx = base + i;
        if (idx < N_NODES) s += cnt[idx];
    }
    lds[tid] = s;
    __syncthreads();
    for (int st = 128; st > 0; st >>= 1) {
        if (tid < st) lds[tid] += lds[tid + st];
        __syncthreads();
    }
    if (tid == 0) bsum[blockIdx.x] = lds[0];
}

// exclusive scan of bsum (tiny)
__global__ __launch_bounds__(64) void k_bscan(int* __restrict__ bsum) {
    if (threadIdx.x == 0) {
        int run = 0;
        for (int i = 0; i < NB_SCAN; ++i) {
            int t = bsum[i];
            bsum[i] = run;
            run += t;
        }
    }
}

// exclusive starts: start[i] = bsum[blk] + local exclusive prefix
__global__ __launch_bounds__(256) void k_starts(const int* __restrict__ cnt,
                                                const int* __restrict__ bsum,
                                                int* __restrict__ start) {
    __shared__ int lds[256];
    const int tid = threadIdx.x;
    int base = blockIdx.x * SCAN_CHUNK + tid * 16;
    int vals[16];
    int s = 0;
#pragma unroll
    for (int i = 0; i < 16; ++i) {
        int idx = base + i;
        int v = (idx < N_NODES) ? cnt[idx] : 0;
        vals[i] = v;
        s += v;
    }
    lds[tid] = s;
    __syncthreads();
    // Hillis-Steele inclusive scan over 256
    for (int st = 1; st < 256; st <<= 1) {
        int t = (tid >= st) ? lds[tid - st] : 0;
        __syncthreads();
        lds[tid] += t;
        __syncthreads();
    }
    int run = bsum[blockIdx.x] + lds[tid] - s;
#pragma unroll
    for (int i = 0; i < 16; ++i) {
        int idx = base + i;
        if (idx < N_NODES) { start[idx] = run; run += vals[i]; }
    }
}

// csr[atomicAdd(&start[row[e]],1)] = col[e]; afterwards start[r] == end(r)
__global__ __launch_bounds__(256) void k_fill(const int* __restrict__ rowIdx,
                                              const int* __restrict__ colIdx,
                                              int* __restrict__ start,
                                              int* __restrict__ csr) {
    int e = blockIdx.x * 256 + threadIdx.x;
    if (e < E_EDGES) {
        int r = rowIdx[e];
        int pos = atomicAdd(&start[r], 1);
        csr[pos] = colIdx[e];
    }
}

// ============ node MLPs (thread-per-row, regs) ============

__global__ __launch_bounds__(256, 2) void k_lin_in(const float* __restrict__ x,
                                                   const float* __restrict__ w,
                                                   const float* __restrict__ b,
                                                   float* __restrict__ h) {
    int r = blockIdx.x * 256 + threadIdx.x;
    if (r >= N_NODES) return;
    float acc[64];
#pragma unroll
    for (int j = 0; j < 64; ++j) acc[j] = b[j];
    const float4* xv = (const float4*)(x + (size_t)r * 128);
    for (int k4 = 0; k4 < 32; ++k4) {
        float4 v = xv[k4];
#pragma unroll
        for (int kk = 0; kk < 4; ++kk) {
            float xk = (&v.x)[kk];
            const float* wrow = w + (k4 * 4 + kk) * 64;
#pragma unroll
            for (int j = 0; j < 64; ++j) acc[j] = fmaf(xk, wrow[j], acc[j]);
        }
    }
    float4* hv = (float4*)(h + (size_t)r * 64);
#pragma unroll
    for (int j4 = 0; j4 < 16; ++j4)
        hv[j4] = make_float4(acc[4 * j4], acc[4 * j4 + 1], acc[4 * j4 + 2], acc[4 * j4 + 3]);
}

// msg (bf16) = relu(relu(h@m1+b1)@m2+b2)
__global__ __launch_bounds__(256, 2) void k_msg(const float* __restrict__ h,
                                                const float* __restrict__ w1,
                                                const float* __restrict__ b1,
                                                const float* __restrict__ w2,
                                                const float* __restrict__ b2,
                                                ushort_t* __restrict__ msg16) {
    int r = blockIdx.x * 256 + threadIdx.x;
    if (r >= N_NODES) return;
    float t[64];
#pragma unroll
    for (int j = 0; j < 64; ++j) t[j] = b1[j];
    const float4* hv = (const float4*)(h + (size_t)r * 64);
    for (int k4 = 0; k4 < 16; ++k4) {
        float4 v = hv[k4];
#pragma unroll
        for (int kk = 0; kk < 4; ++kk) {
            float xk = (&v.x)[kk];
            const float* wrow = w1 + (k4 * 4 + kk) * 64;
#pragma unroll
            for (int j = 0; j < 64; ++j) t[j] = fmaf(xk, wrow[j], t[j]);
        }
    }
#pragma unroll
    for (int j = 0; j < 64; ++j) t[j] = fmaxf(t[j], 0.0f);
    for (int c = 0; c < 4; ++c) {
        float o[16];
#pragma unroll
        for (int j = 0; j < 16; ++j) o[j] = b2[c * 16 + j];
#pragma unroll
        for (int k = 0; k < 64; ++k) {
            const float* wrow = w2 + k * 64 + c * 16;
#pragma unroll
            for (int j = 0; j < 16; ++j) o[j] = fmaf(t[k], wrow[j], o[j]);
        }
#pragma unroll
        for (int j = 0; j < 16; ++j) o[j] = fmaxf(o[j], 0.0f);
        uint4* mv = (uint4*)(msg16 + (size_t)r * 64 + c * 16);
        mv[0] = make_uint4(bf16_2(o[0], o[1]), bf16_2(o[2], o[3]),
                           bf16_2(o[4], o[5]), bf16_2(o[6], o[7]));
        mv[1] = make_uint4(bf16_2(o[8], o[9]), bf16_2(o[10], o[11]),
                           bf16_2(o[12], o[13]), bf16_2(o[14], o[15]));
    }
}

// ============ aggregation: gather (wave per node, bf16 msg) ============
__global__ __launch_bounds__(256) void k_gather(const int* __restrict__ start,
                                                const int* __restrict__ csr,
                                                const ushort_t* __restrict__ msg16,
                                                float* __restrict__ agg) {
    const int lane = threadIdx.x & 63;
    const int wid  = threadIdx.x >> 6;
    int r = blockIdx.x * 4 + wid;
    if (r >= N_NODES) return;
    int b = (r == 0) ? 0 : start[r - 1];
    int e0 = start[r];
    float acc0 = 0.0f, acc1 = 0.0f;
    for (int base = b; base < e0; base += 64) {
        int n = e0 - base;
        if (n > 64) n = 64;
        int c = 0;
        if (base + lane < e0) c = csr[base + lane];
        int j = 0;
        for (; j + 4 <= n; j += 4) {
            int c0 = __shfl(c, j, 64);
            int c1 = __shfl(c, j + 1, 64);
            int c2 = __shfl(c, j + 2, 64);
            int c3 = __shfl(c, j + 3, 64);
            float l0 = bf16_f(msg16[(size_t)c0 * 64 + lane]);
            float l1 = bf16_f(msg16[(size_t)c1 * 64 + lane]);
            float l2 = bf16_f(msg16[(size_t)c2 * 64 + lane]);
            float l3 = bf16_f(msg16[(size_t)c3 * 64 + lane]);
            acc0 += l0 + l2;
            acc1 += l1 + l3;
        }
        for (; j < n; ++j) {
            int cj = __shfl(c, j, 64);
            acc0 += bf16_f(msg16[(size_t)cj * 64 + lane]);
        }
    }
    agg[(size_t)r * 64 + lane] = acc0 + acc1;
}

// ------- h += relu(concat(h, agg/clip(deg,1)) @ u1 + b1) @ u2 + b2 ----------
__global__ __launch_bounds__(256, 2) void k_update(float* __restrict__ h,
                                                   const float* __restrict__ agg,
                                                   const int* __restrict__ cnt,
                                                   const float* __restrict__ u1,
                                                   const float* __restrict__ b1,
                                                   const float* __restrict__ u2,
                                                   const float* __restrict__ b2) {
    int r = blockIdx.x * 256 + threadIdx.x;
    if (r >= N_NODES) return;
    float t[64];
#pragma unroll
    for (int j = 0; j < 64; ++j) t[j] = b1[j];
    const float4* hv = (const float4*)(h + (size_t)r * 64);
    for (int k4 = 0; k4 < 16; ++k4) {
        float4 v = hv[k4];
#pragma unroll
        for (int kk = 0; kk < 4; ++kk) {
            float xk = (&v.x)[kk];
            const float* wrow = u1 + (k4 * 4 + kk) * 64;
#pragma unroll
            for (int j = 0; j < 64; ++j) t[j] = fmaf(xk, wrow[j], t[j]);
        }
    }
    float dv = (float)cnt[r];
    float inv = 1.0f / fmaxf(dv, 1.0f);
    const float4* av4 = (const float4*)(agg + (size_t)r * 64);
    for (int k4 = 0; k4 < 16; ++k4) {
        float4 v = av4[k4];
#pragma unroll
        for (int kk = 0; kk < 4; ++kk) {
            float xk = (&v.x)[kk] * inv;
            const float* wrow = u1 + (64 + k4 * 4 + kk) * 64;
#pragma unroll
            for (int j = 0; j < 64; ++j) t[j] = fmaf(xk, wrow[j], t[j]);
        }
    }
#pragma unroll
    for (int j = 0; j < 64; ++j) t[j] = fmaxf(t[j], 0.0f);
    for (int c = 0; c < 4; ++c) {
        float o[16];
#pragma unroll
        for (int j = 0; j < 16; ++j) o[j] = b2[c * 16 + j];
#pragma unroll
        for (int k = 0; k < 64; ++k) {
            const float* wrow = u2 + k * 64 + c * 16;
#pragma unroll
            for (int j = 0; j < 16; ++j) o[j] = fmaf(t[k], wrow[j], o[j]);
        }
        float4* hw = (float4*)(h + (size_t)r * 64 + c * 16);
#pragma unroll
        for (int j4 = 0; j4 < 4; ++j4) {
            float4 old = hw[j4];
            hw[j4] = make_float4(old.x + o[4 * j4], old.y + o[4 * j4 + 1],
                                 old.z + o[4 * j4 + 2], old.w + o[4 * j4 + 3]);
        }
    }
}

// ------- hA(bf16) = h@h1w[0:64] + deg*h1w[128] + h1b ; hB(bf16) = h@h1w[64:128] + deg*h1w[129]
__global__ __launch_bounds__(256, 2) void k_headpre(const float* __restrict__ h,
                                                    const int* __restrict__ cnt,
                                                    const float* __restrict__ w,
                                                    const float* __restrict__ b,
                                                    ushort_t* __restrict__ hA16,
                                                    ushort_t* __restrict__ hB16) {
    int r = blockIdx.x * 256 + threadIdx.x;
    if (r >= N_NODES) return;
    float dv = (float)cnt[r];
    const float4* hv = (const float4*)(h + (size_t)r * 64);
    {
        float acc[64];
#pragma unroll
        for (int j = 0; j < 64; ++j) acc[j] = b[j] + dv * w[128 * 64 + j];
        for (int k4 = 0; k4 < 16; ++k4) {
            float4 v = hv[k4];
#pragma unroll
            for (int kk = 0; kk < 4; ++kk) {
                float xk = (&v.x)[kk];
                const float* wrow = w + (k4 * 4 + kk) * 64;
#pragma unroll
                for (int j = 0; j < 64; ++j) acc[j] = fmaf(xk, wrow[j], acc[j]);
            }
        }
        uint4* ov = (uint4*)(hA16 + (size_t)r * 64);
#pragma unroll
        for (int j8 = 0; j8 < 8; ++j8)
            ov[j8] = make_uint4(bf16_2(acc[8 * j8 + 0], acc[8 * j8 + 1]),
                                bf16_2(acc[8 * j8 + 2], acc[8 * j8 + 3]),
                                bf16_2(acc[8 * j8 + 4], acc[8 * j8 + 5]),
                                bf16_2(acc[8 * j8 + 6], acc[8 * j8 + 7]));
    }
    {
        float acc[64];
#pragma unroll
        for (int j = 0; j < 64; ++j) acc[j] = dv * w[129 * 64 + j];
        for (int k4 = 0; k4 < 16; ++k4) {
            float4 v = hv[k4];
#pragma unroll
            for (int kk = 0; kk < 4; ++kk) {
                float xk = (&v.x)[kk];
                const float* wrow = w + (64 + k4 * 4 + kk) * 64;
#pragma unroll
                for (int j = 0; j < 64; ++j) acc[j] = fmaf(xk, wrow[j], acc[j]);
            }
        }
        uint4* ov = (uint4*)(hB16 + (size_t)r * 64);
#pragma unroll
        for (int j8 = 0; j8 < 8; ++j8)
            ov[j8] = make_uint4(bf16_2(acc[8 * j8 + 0], acc[8 * j8 + 1]),
                                bf16_2(acc[8 * j8 + 2], acc[8 * j8 + 3]),
                                bf16_2(acc[8 * j8 + 4], acc[8 * j8 + 5]),
                                bf16_2(acc[8 * j8 + 6], acc[8 * j8 + 7]));
    }
}

// ------- out[e] = out[e+HALF] = softplus(relu(hA[src]+hB[dst]) . h2w + h2b) + 1e-6 ------
__global__ __launch_bounds__(256) void k_head(const int* __restrict__ rowIdx,
                                              const int* __restrict__ colIdx,
                                              const ushort_t* __restrict__ hA16,
                                              const ushort_t* __restrict__ hB16,
                                              const float* __restrict__ w2,
                                              const float* __restrict__ b2,
                                              float* __restrict__ out) {
    const int lane = threadIdx.x & 63;
    const int sub = lane & 15;
    const int grp = lane >> 4;
    const int waveId = (blockIdx.x * 256 + threadIdx.x) >> 6;
    const int step = gridDim.x * 4 * 4;
    const float4 wv = *(const float4*)(w2 + sub * 4);
    const float b2v = b2[0];
    for (int e = waveId * 4 + grp; e < HALF_E; e += step) {
        int s = rowIdx[e];
        int d = colIdx[e];
        ushort4 a4 = *(const ushort4*)(hA16 + (size_t)s * 64 + sub * 4);
        ushort4 b4 = *(const ushort4*)(hB16 + (size_t)d * 64 + sub * 4);
        float t0 = fmaxf(bf16_f(a4.x) + bf16_f(b4.x), 0.0f);
        float t1 = fmaxf(bf16_f(a4.y) + bf16_f(b4.y), 0.0f);
        float t2 = fmaxf(bf16_f(a4.z) + bf16_f(b4.z), 0.0f);
        float t3 = fmaxf(bf16_f(a4.w) + bf16_f(b4.w), 0.0f);
        float p = t0 * wv.x + t1 * wv.y + t2 * wv.z + t3 * wv.w;
        p += __shfl_xor(p, 1);
        p += __shfl_xor(p, 2);
        p += __shfl_xor(p, 4);
        p += __shfl_xor(p, 8);
        if (sub == 0) {
            float sv = p + b2v;
            float sp = fmaxf(sv, 0.0f) + log1pf(expf(-fabsf(sv)));
            float wvv = sp + 1e-6f;
            out[e] = wvv;
            out[e + HALF_E] = wvv;
        }
    }
}

extern "C" void kernel_launch(void* const* d_in, const int* in_sizes, int n_in,
                              void* d_out, int out_size, void* d_ws, size_t ws_size,
                              hipStream_t stream) {
    const float* x      = (const float*)d_in[0];
    const int*   rowIdx = (const int*)d_in[1];
    const int*   colIdx = rowIdx + E_EDGES;
    const float* w_in   = (const float*)d_in[2];
    const float* b_in   = (const float*)d_in[3];
    const float* l0_m1w = (const float*)d_in[4];
    const float* l0_m1b = (const float*)d_in[5];
    const float* l0_m2w = (const float*)d_in[6];
    const float* l0_m2b = (const float*)d_in[7];
    const float* l0_u1w = (const float*)d_in[8];
    const float* l0_u1b = (const float*)d_in[9];
    const float* l0_u2w = (const float*)d_in[10];
    const float* l0_u2b = (const float*)d_in[11];
    const float* l1_m1w = (const float*)d_in[12];
    const float* l1_m1b = (const float*)d_in[13];
    const float* l1_m2w = (const float*)d_in[14];
    const float* l1_m2b = (const float*)d_in[15];
    const float* l1_u1w = (const float*)d_in[16];
    const float* l1_u1b = (const float*)d_in[17];
    const float* l1_u2w = (const float*)d_in[18];
    const float* l1_u2b = (const float*)d_in[19];
    const float* h1w    = (const float*)d_in[20];
    const float* h1b    = (const float*)d_in[21];
    const float* h2w    = (const float*)d_in[22];
    const float* h2b    = (const float*)d_in[23];

    float* out = (float*)d_out;

    float*    h     = (float*)d_ws;                         // N x 64 f32
    float*    agg   = h + (size_t)N_NODES * 64;             // N x 64 f32 (later hA16/hB16)
    ushort_t* msg16 = (ushort_t*)(agg + (size_t)N_NODES * 64); // N x 64 bf16
    int*      cnt   = (int*)(msg16 + (size_t)N_NODES * 64); // N
    int*      start = cnt + N_NODES;                        // N
    int*      bsum  = start + N_NODES;                      // NB_SCAN
    int*      csr   = bsum + 64;                            // E

    ushort_t* hA16 = (ushort_t*)agg;                        // N x 64 bf16
    ushort_t* hB16 = hA16 + (size_t)N_NODES * 64;           // N x 64 bf16

    const int nodeBlocks = (N_NODES + 255) / 256;
    const int edgeBlocks = (E_EDGES + 255) / 256;
    const int gatherBlocks = (N_NODES + 3) / 4;

    // ---- CSR build ----
    hipMemsetAsync(cnt, 0, (size_t)N_NODES * sizeof(int), stream);
    k_hist<<<edgeBlocks, 256, 0, stream>>>(rowIdx, cnt);
    k_bsum<<<NB_SCAN, 256, 0, stream>>>(cnt, bsum);
    k_bscan<<<1, 64, 0, stream>>>(bsum);
    k_starts<<<NB_SCAN, 256, 0, stream>>>(cnt, bsum, start);
    k_fill<<<edgeBlocks, 256, 0, stream>>>(rowIdx, colIdx, start, csr);

    k_lin_in<<<nodeBlocks, 256, 0, stream>>>(x, w_in, b_in, h);

    // ---- layer 0 ----
    k_msg<<<nodeBlocks, 256, 0, stream>>>(h, l0_m1w, l0_m1b, l0_m2w, l0_m2b, msg16);
    k_gather<<<gatherBlocks, 256, 0, stream>>>(start, csr, msg16, agg);
    k_update<<<nodeBlocks, 256, 0, stream>>>(h, agg, cnt, l0_u1w, l0_u1b, l0_u2w, l0_u2b);

    // ---- layer 1 ----
    k_msg<<<nodeBlocks, 256, 0, stream>>>(h, l1_m1w, l1_m1b, l1_m2w, l1_m2b, msg16);
    k_gather<<<gatherBlocks, 256, 0, stream>>>(start, csr, msg16, agg);
    k_update<<<nodeBlocks, 256, 0, stream>>>(h, agg, cnt, l1_u1w, l1_u1b, l1_u2w, l1_u2b);

    // ---- head ----
    k_headpre<<<nodeBlocks, 256, 0, stream>>>(h, cnt, h1w, h1b, hA16, hB16);
    k_head<<<4096, 256, 0, stream>>>(rowIdx, colIdx, hA16, hB16, h2w, h2b, out);
}

// Round 5
// 629.725 us; speedup vs baseline: 5.0803x; 1.1095x over previous
//
#include <hip/hip_runtime.h>
#include <math.h>

#define N_NODES 100000
#define E_EDGES 1600000
#define HALF_E  (E_EDGES / 2)
#define SCAN_CHUNK 4096
#define NB_SCAN ((N_NODES + SCAN_CHUNK - 1) / SCAN_CHUNK)

#define NBUCK 256
#define ROWS_PER_BUCKET ((N_NODES + NBUCK - 1) / NBUCK)   // 391
#define EDGES_PER_BLK_A 4096
#define NBLK_A ((E_EDGES + EDGES_PER_BLK_A - 1) / EDGES_PER_BLK_A)  // 391

typedef unsigned short ushort_t;

// ---- bf16 helpers (RNE pack, cheap unpack) ----
__device__ __forceinline__ unsigned bf16_1(float f) {
    unsigned u = __float_as_uint(f);
    return (u + 0x7fffu + ((u >> 16) & 1u)) >> 16;
}
__device__ __forceinline__ unsigned bf16_2(float a, float b) {
    return bf16_1(a) | (bf16_1(b) << 16);
}
__device__ __forceinline__ float bf16_f(ushort_t us) {
    return __uint_as_float(((unsigned)us) << 16);
}

// ============ CSR build ============

__global__ __launch_bounds__(256) void k_hist(const int* __restrict__ rowIdx,
                                              int* __restrict__ cnt) {
    int e = blockIdx.x * 256 + threadIdx.x;
    if (e < E_EDGES) atomicAdd(&cnt[rowIdx[e]], 1);
}

__global__ __launch_bounds__(256) void k_bsum(const int* __restrict__ cnt,
                                              int* __restrict__ bsum) {
    __shared__ int lds[256];
    const int tid = threadIdx.x;
    int base = blockIdx.x * SCAN_CHUNK + tid * 16;
    int s = 0;
#pragma unroll
    for (int i = 0; i < 16; ++i) {
        int idx = base + i;
        if (idx < N_NODES) s += cnt[idx];
    }
    lds[tid] = s;
    __syncthreads();
    for (int st = 128; st > 0; st >>= 1) {
        if (tid < st) lds[tid] += lds[tid + st];
        __syncthreads();
    }
    if (tid == 0) bsum[blockIdx.x] = lds[0];
}

// exclusive scan of bsum (tiny); also plants start[N] = E
__global__ __launch_bounds__(64) void k_bscan(int* __restrict__ bsum,
                                              int* __restrict__ start) {
    if (threadIdx.x == 0) {
        int run = 0;
        for (int i = 0; i < NB_SCAN; ++i) {
            int t = bsum[i];
            bsum[i] = run;
            run += t;
        }
        start[N_NODES] = E_EDGES;
    }
}

// exclusive starts (pristine: start[r] = begin of row r, start[N] = E)
__global__ __launch_bounds__(256) void k_starts(const int* __restrict__ cnt,
                                                const int* __restrict__ bsum,
                                                int* __restrict__ start) {
    __shared__ int lds[256];
    const int tid = threadIdx.x;
    int base = blockIdx.x * SCAN_CHUNK + tid * 16;
    int vals[16];
    int s = 0;
#pragma unroll
    for (int i = 0; i < 16; ++i) {
        int idx = base + i;
        int v = (idx < N_NODES) ? cnt[idx] : 0;
        vals[i] = v;
        s += v;
    }
    lds[tid] = s;
    __syncthreads();
    for (int st = 1; st < 256; st <<= 1) {
        int t = (tid >= st) ? lds[tid - st] : 0;
        __syncthreads();
        lds[tid] += t;
        __syncthreads();
    }
    int run = bsum[blockIdx.x] + lds[tid] - s;
#pragma unroll
    for (int i = 0; i < 16; ++i) {
        int idx = base + i;
        if (idx < N_NODES) { start[idx] = run; run += vals[i]; }
    }
}

// cursorA[b] = begin of bucket b in csr/pairs space
__global__ __launch_bounds__(256) void k_initcur(const int* __restrict__ start,
                                                 int* __restrict__ cursorA) {
    int b = threadIdx.x;
    cursorA[b] = start[b * ROWS_PER_BUCKET];
}

// Pass A: bucket edges into pairs[] (grouped by 391-row buckets), coalesced runs.
__global__ __launch_bounds__(256) void k_bucketA(const int* __restrict__ rowIdx,
                                                 const int* __restrict__ colIdx,
                                                 int* __restrict__ cursorA,
                                                 uint2* __restrict__ pairs) {
    __shared__ uint2 stage[EDGES_PER_BLK_A];
    __shared__ unsigned char bmap[EDGES_PER_BLK_A];
    __shared__ int cntL[NBUCK], scanEx[NBUCK], cur[NBUCK], posG[NBUCK];
    const int tid = threadIdx.x;
    const int e0 = blockIdx.x * EDGES_PER_BLK_A;
    const int n = min(EDGES_PER_BLK_A, E_EDGES - e0);

    cntL[tid] = 0;
    __syncthreads();
    for (int i = tid; i < n; i += 256) {
        int b = rowIdx[e0 + i] / ROWS_PER_BUCKET;
        atomicAdd(&cntL[b], 1);
    }
    __syncthreads();
    // inclusive scan of cntL
    int myc = cntL[tid];
    scanEx[tid] = myc;
    __syncthreads();
    for (int st = 1; st < 256; st <<= 1) {
        int t = (tid >= st) ? scanEx[tid - st] : 0;
        __syncthreads();
        scanEx[tid] += t;
        __syncthreads();
    }
    int ex = scanEx[tid] - myc;
    __syncthreads();
    scanEx[tid] = ex;
    cur[tid] = ex;
    if (myc) posG[tid] = atomicAdd(&cursorA[tid], myc);
    __syncthreads();
    for (int i = tid; i < n; i += 256) {
        int r = rowIdx[e0 + i];
        int c = colIdx[e0 + i];
        int b = r / ROWS_PER_BUCKET;
        int slot = atomicAdd(&cur[b], 1);
        stage[slot] = make_uint2((unsigned)c, (unsigned)r);
        bmap[slot] = (unsigned char)b;
    }
    __syncthreads();
    for (int i = tid; i < n; i += 256) {
        int b = bmap[i];
        int dst = posG[b] + (i - scanEx[b]);
        pairs[dst] = stage[i];
    }
}

// Pass B: within each bucket, scatter cols to final csr position (L2-hot window).
__global__ __launch_bounds__(256) void k_bucketB(const int* __restrict__ start,
                                                 const uint2* __restrict__ pairs,
                                                 int* __restrict__ csr) {
    __shared__ int cur[ROWS_PER_BUCKET];
    const int tid = threadIdx.x;
    const int rowbase = blockIdx.x * ROWS_PER_BUCKET;
    const int nrows = min(ROWS_PER_BUCKET, N_NODES - rowbase);
    for (int i = tid; i < nrows; i += 256) cur[i] = start[rowbase + i];
    __syncthreads();
    const int bBeg = start[rowbase];
    const int bEnd = start[rowbase + nrows];
    for (int i = bBeg + tid; i < bEnd; i += 256) {
        uint2 p = pairs[i];
        int pos = atomicAdd(&cur[(int)p.y - rowbase], 1);
        csr[pos] = (int)p.x;
    }
}

// ============ fused node MLPs (thread-per-row, regs) ============

// h = x@w_in+b_in ; msg16 = relu(relu(h@m1+b1)@m2+b2)
__global__ __launch_bounds__(256, 2) void k_lin_msg(const float* __restrict__ x,
                                                    const float* __restrict__ w,
                                                    const float* __restrict__ b,
                                                    const float* __restrict__ m1w,
                                                    const float* __restrict__ m1b,
                                                    const float* __restrict__ m2w,
                                                    const float* __restrict__ m2b,
                                                    float* __restrict__ h,
                                                    ushort_t* __restrict__ msg16) {
    int r = blockIdx.x * 256 + threadIdx.x;
    if (r >= N_NODES) return;
    float acc[64];
#pragma unroll
    for (int j = 0; j < 64; ++j) acc[j] = b[j];
    const float4* xv = (const float4*)(x + (size_t)r * 128);
    for (int k4 = 0; k4 < 32; ++k4) {
        float4 v = xv[k4];
#pragma unroll
        for (int kk = 0; kk < 4; ++kk) {
            float xk = (&v.x)[kk];
            const float* wrow = w + (k4 * 4 + kk) * 64;
#pragma unroll
            for (int j = 0; j < 64; ++j) acc[j] = fmaf(xk, wrow[j], acc[j]);
        }
    }
    float4* hv = (float4*)(h + (size_t)r * 64);
#pragma unroll
    for (int j4 = 0; j4 < 16; ++j4)
        hv[j4] = make_float4(acc[4 * j4], acc[4 * j4 + 1], acc[4 * j4 + 2], acc[4 * j4 + 3]);
    // msg phase 1
    float t[64];
#pragma unroll
    for (int j = 0; j < 64; ++j) t[j] = m1b[j];
#pragma unroll
    for (int k = 0; k < 64; ++k) {
        float xk = acc[k];
        const float* wrow = m1w + k * 64;
#pragma unroll
        for (int j = 0; j < 64; ++j) t[j] = fmaf(xk, wrow[j], t[j]);
    }
#pragma unroll
    for (int j = 0; j < 64; ++j) t[j] = fmaxf(t[j], 0.0f);
    // msg phase 2 (chunks of 16)
    for (int c = 0; c < 4; ++c) {
        float o[16];
#pragma unroll
        for (int j = 0; j < 16; ++j) o[j] = m2b[c * 16 + j];
#pragma unroll
        for (int k = 0; k < 64; ++k) {
            const float* wrow = m2w + k * 64 + c * 16;
#pragma unroll
            for (int j = 0; j < 16; ++j) o[j] = fmaf(t[k], wrow[j], o[j]);
        }
#pragma unroll
        for (int j = 0; j < 16; ++j) o[j] = fmaxf(o[j], 0.0f);
        uint4* mv = (uint4*)(msg16 + (size_t)r * 64 + c * 16);
        mv[0] = make_uint4(bf16_2(o[0], o[1]), bf16_2(o[2], o[3]),
                           bf16_2(o[4], o[5]), bf16_2(o[6], o[7]));
        mv[1] = make_uint4(bf16_2(o[8], o[9]), bf16_2(o[10], o[11]),
                           bf16_2(o[12], o[13]), bf16_2(o[14], o[15]));
    }
}

// ============ aggregation: gather (wave per node, bf16 msg) ============
__global__ __launch_bounds__(256) void k_gather(const int* __restrict__ start,
                                                const int* __restrict__ csr,
                                                const ushort_t* __restrict__ msg16,
                                                float* __restrict__ agg) {
    const int lane = threadIdx.x & 63;
    const int wid  = threadIdx.x >> 6;
    int r = blockIdx.x * 4 + wid;
    if (r >= N_NODES) return;
    int b = start[r];
    int e0 = start[r + 1];
    float acc0 = 0.0f, acc1 = 0.0f;
    for (int base = b; base < e0; base += 64) {
        int n = e0 - base;
        if (n > 64) n = 64;
        int c = 0;
        if (base + lane < e0) c = csr[base + lane];
        int j = 0;
        for (; j + 4 <= n; j += 4) {
            int c0 = __shfl(c, j, 64);
            int c1 = __shfl(c, j + 1, 64);
            int c2 = __shfl(c, j + 2, 64);
            int c3 = __shfl(c, j + 3, 64);
            float l0 = bf16_f(msg16[(size_t)c0 * 64 + lane]);
            float l1 = bf16_f(msg16[(size_t)c1 * 64 + lane]);
            float l2 = bf16_f(msg16[(size_t)c2 * 64 + lane]);
            float l3 = bf16_f(msg16[(size_t)c3 * 64 + lane]);
            acc0 += l0 + l2;
            acc1 += l1 + l3;
        }
        for (; j < n; ++j) {
            int cj = __shfl(c, j, 64);
            acc0 += bf16_f(msg16[(size_t)cj * 64 + lane]);
        }
    }
    agg[(size_t)r * 64 + lane] = acc0 + acc1;
}

// ---- update layer0 then msg layer1, fused ----
__global__ __launch_bounds__(256, 2) void k_update_msg(float* __restrict__ h,
                                                       const float* __restrict__ agg,
                                                       const int* __restrict__ cnt,
                                                       const float* __restrict__ u1,
                                                       const float* __restrict__ b1,
                                                       const float* __restrict__ u2,
                                                       const float* __restrict__ b2,
                                                       const float* __restrict__ m1w,
                                                       const float* __restrict__ m1b,
                                                       const float* __restrict__ m2w,
                                                       const float* __restrict__ m2b,
                                                       ushort_t* __restrict__ msg16) {
    int r = blockIdx.x * 256 + threadIdx.x;
    if (r >= N_NODES) return;
    float t[64];
#pragma unroll
    for (int j = 0; j < 64; ++j) t[j] = b1[j];
    const float4* hv = (const float4*)(h + (size_t)r * 64);
    for (int k4 = 0; k4 < 16; ++k4) {
        float4 v = hv[k4];
#pragma unroll
        for (int kk = 0; kk < 4; ++kk) {
            float xk = (&v.x)[kk];
            const float* wrow = u1 + (k4 * 4 + kk) * 64;
#pragma unroll
            for (int j = 0; j < 64; ++j) t[j] = fmaf(xk, wrow[j], t[j]);
        }
    }
    float inv = 1.0f / fmaxf((float)cnt[r], 1.0f);
    const float4* av4 = (const float4*)(agg + (size_t)r * 64);
    for (int k4 = 0; k4 < 16; ++k4) {
        float4 v = av4[k4];
#pragma unroll
        for (int kk = 0; kk < 4; ++kk) {
            float xk = (&v.x)[kk] * inv;
            const float* wrow = u1 + (64 + k4 * 4 + kk) * 64;
#pragma unroll
            for (int j = 0; j < 64; ++j) t[j] = fmaf(xk, wrow[j], t[j]);
        }
    }
#pragma unroll
    for (int j = 0; j < 64; ++j) t[j] = fmaxf(t[j], 0.0f);
    // o = t @ u2 + b2  (full row)
    float o[64];
#pragma unroll
    for (int j = 0; j < 64; ++j) o[j] = b2[j];
#pragma unroll
    for (int k = 0; k < 64; ++k) {
        float xk = t[k];
        const float* wrow = u2 + k * 64;
#pragma unroll
        for (int j = 0; j < 64; ++j) o[j] = fmaf(xk, wrow[j], o[j]);
    }
    // residual: reload h row (L1/L2-hot), h_new in o
    for (int k4 = 0; k4 < 16; ++k4) {
        float4 v = hv[k4];
        o[4 * k4 + 0] += v.x;
        o[4 * k4 + 1] += v.y;
        o[4 * k4 + 2] += v.z;
        o[4 * k4 + 3] += v.w;
    }
    float4* hw = (float4*)(h + (size_t)r * 64);
#pragma unroll
    for (int j4 = 0; j4 < 16; ++j4)
        hw[j4] = make_float4(o[4 * j4], o[4 * j4 + 1], o[4 * j4 + 2], o[4 * j4 + 3]);
    // msg layer1 phase 1 (reuse t)
#pragma unroll
    for (int j = 0; j < 64; ++j) t[j] = m1b[j];
#pragma unroll
    for (int k = 0; k < 64; ++k) {
        float xk = o[k];
        const float* wrow = m1w + k * 64;
#pragma unroll
        for (int j = 0; j < 64; ++j) t[j] = fmaf(xk, wrow[j], t[j]);
    }
#pragma unroll
    for (int j = 0; j < 64; ++j) t[j] = fmaxf(t[j], 0.0f);
    // msg phase 2 chunks
    for (int c = 0; c < 4; ++c) {
        float oo[16];
#pragma unroll
        for (int j = 0; j < 16; ++j) oo[j] = m2b[c * 16 + j];
#pragma unroll
        for (int k = 0; k < 64; ++k) {
            const float* wrow = m2w + k * 64 + c * 16;
#pragma unroll
            for (int j = 0; j < 16; ++j) oo[j] = fmaf(t[k], wrow[j], oo[j]);
        }
#pragma unroll
        for (int j = 0; j < 16; ++j) oo[j] = fmaxf(oo[j], 0.0f);
        uint4* mv = (uint4*)(msg16 + (size_t)r * 64 + c * 16);
        mv[0] = make_uint4(bf16_2(oo[0], oo[1]), bf16_2(oo[2], oo[3]),
                           bf16_2(oo[4], oo[5]), bf16_2(oo[6], oo[7]));
        mv[1] = make_uint4(bf16_2(oo[8], oo[9]), bf16_2(oo[10], oo[11]),
                           bf16_2(oo[12], oo[13]), bf16_2(oo[14], oo[15]));
    }
}

// ---- update layer1 then head precompute, fused (h_new never hits memory) ----
__global__ __launch_bounds__(256, 2) void k_update_headpre(const float* __restrict__ h,
                                                           const float* __restrict__ agg,
                                                           const int* __restrict__ cnt,
                                                           const float* __restrict__ u1,
                                                           const float* __restrict__ b1,
                                                           const float* __restrict__ u2,
                                                           const float* __restrict__ b2,
                                                           const float* __restrict__ hw1,
                                                           const float* __restrict__ hb1,
                                                           ushort_t* __restrict__ hA16,
                                                           ushort_t* __restrict__ hB16) {
    int r = blockIdx.x * 256 + threadIdx.x;
    if (r >= N_NODES) return;
    float dv = (float)cnt[r];
    float t[64];
#pragma unroll
    for (int j = 0; j < 64; ++j) t[j] = b1[j];
    const float4* hv = (const float4*)(h + (size_t)r * 64);
    for (int k4 = 0; k4 < 16; ++k4) {
        float4 v = hv[k4];
#pragma unroll
        for (int kk = 0; kk < 4; ++kk) {
            float xk = (&v.x)[kk];
            const float* wrow = u1 + (k4 * 4 + kk) * 64;
#pragma unroll
            for (int j = 0; j < 64; ++j) t[j] = fmaf(xk, wrow[j], t[j]);
        }
    }
    float inv = 1.0f / fmaxf(dv, 1.0f);
    const float4* av4 = (const float4*)(agg + (size_t)r * 64);
    for (int k4 = 0; k4 < 16; ++k4) {
        float4 v = av4[k4];
#pragma unroll
        for (int kk = 0; kk < 4; ++kk) {
            float xk = (&v.x)[kk] * inv;
            const float* wrow = u1 + (64 + k4 * 4 + kk) * 64;
#pragma unroll
            for (int j = 0; j < 64; ++j) t[j] = fmaf(xk, wrow[j], t[j]);
        }
    }
#pragma unroll
    for (int j = 0; j < 64; ++j) t[j] = fmaxf(t[j], 0.0f);
    float o[64];
#pragma unroll
    for (int j = 0; j < 64; ++j) o[j] = b2[j];
#pragma unroll
    for (int k = 0; k < 64; ++k) {
        float xk = t[k];
        const float* wrow = u2 + k * 64;
#pragma unroll
        for (int j = 0; j < 64; ++j) o[j] = fmaf(xk, wrow[j], o[j]);
    }
    for (int k4 = 0; k4 < 16; ++k4) {
        float4 v = hv[k4];
        o[4 * k4 + 0] += v.x;
        o[4 * k4 + 1] += v.y;
        o[4 * k4 + 2] += v.z;
        o[4 * k4 + 3] += v.w;
    }
    // headpre A (reuse t)
#pragma unroll
    for (int j = 0; j < 64; ++j) t[j] = hb1[j] + dv * hw1[128 * 64 + j];
#pragma unroll
    for (int k = 0; k < 64; ++k) {
        float xk = o[k];
        const float* wrow = hw1 + k * 64;
#pragma unroll
        for (int j = 0; j < 64; ++j) t[j] = fmaf(xk, wrow[j], t[j]);
    }
    {
        uint4* ov = (uint4*)(hA16 + (size_t)r * 64);
#pragma unroll
        for (int j8 = 0; j8 < 8; ++j8)
            ov[j8] = make_uint4(bf16_2(t[8 * j8 + 0], t[8 * j8 + 1]),
                                bf16_2(t[8 * j8 + 2], t[8 * j8 + 3]),
                                bf16_2(t[8 * j8 + 4], t[8 * j8 + 5]),
                                bf16_2(t[8 * j8 + 6], t[8 * j8 + 7]));
    }
    // headpre B
#pragma unroll
    for (int j = 0; j < 64; ++j) t[j] = dv * hw1[129 * 64 + j];
#pragma unroll
    for (int k = 0; k < 64; ++k) {
        float xk = o[k];
        const float* wrow = hw1 + (64 + k) * 64;
#pragma unroll
        for (int j = 0; j < 64; ++j) t[j] = fmaf(xk, wrow[j], t[j]);
    }
    {
        uint4* ov = (uint4*)(hB16 + (size_t)r * 64);
#pragma unroll
        for (int j8 = 0; j8 < 8; ++j8)
            ov[j8] = make_uint4(bf16_2(t[8 * j8 + 0], t[8 * j8 + 1]),
                                bf16_2(t[8 * j8 + 2], t[8 * j8 + 3]),
                                bf16_2(t[8 * j8 + 4], t[8 * j8 + 5]),
                                bf16_2(t[8 * j8 + 6], t[8 * j8 + 7]));
    }
}

// ------- out[e] = out[e+HALF] = softplus(relu(hA[src]+hB[dst]) . h2w + h2b) + 1e-6 ------
__global__ __launch_bounds__(256) void k_head(const int* __restrict__ rowIdx,
                                              const int* __restrict__ colIdx,
                                              const ushort_t* __restrict__ hA16,
                                              const ushort_t* __restrict__ hB16,
                                              const float* __restrict__ w2,
                                              const float* __restrict__ b2,
                                              float* __restrict__ out) {
    const int lane = threadIdx.x & 63;
    const int sub = lane & 15;
    const int grp = lane >> 4;
    const int waveId = (blockIdx.x * 256 + threadIdx.x) >> 6;
    const int step = gridDim.x * 4 * 4;
    const float4 wv = *(const float4*)(w2 + sub * 4);
    const float b2v = b2[0];
    for (int e = waveId * 4 + grp; e < HALF_E; e += step) {
        int s = rowIdx[e];
        int d = colIdx[e];
        ushort4 a4 = *(const ushort4*)(hA16 + (size_t)s * 64 + sub * 4);
        ushort4 b4 = *(const ushort4*)(hB16 + (size_t)d * 64 + sub * 4);
        float t0 = fmaxf(bf16_f(a4.x) + bf16_f(b4.x), 0.0f);
        float t1 = fmaxf(bf16_f(a4.y) + bf16_f(b4.y), 0.0f);
        float t2 = fmaxf(bf16_f(a4.z) + bf16_f(b4.z), 0.0f);
        float t3 = fmaxf(bf16_f(a4.w) + bf16_f(b4.w), 0.0f);
        float p = t0 * wv.x + t1 * wv.y + t2 * wv.z + t3 * wv.w;
        p += __shfl_xor(p, 1);
        p += __shfl_xor(p, 2);
        p += __shfl_xor(p, 4);
        p += __shfl_xor(p, 8);
        if (sub == 0) {
            float sv = p + b2v;
            float sp = fmaxf(sv, 0.0f) + log1pf(expf(-fabsf(sv)));
            float wvv = sp + 1e-6f;
            out[e] = wvv;
            out[e + HALF_E] = wvv;
        }
    }
}

extern "C" void kernel_launch(void* const* d_in, const int* in_sizes, int n_in,
                              void* d_out, int out_size, void* d_ws, size_t ws_size,
                              hipStream_t stream) {
    const float* x      = (const float*)d_in[0];
    const int*   rowIdx = (const int*)d_in[1];
    const int*   colIdx = rowIdx + E_EDGES;
    const float* w_in   = (const float*)d_in[2];
    const float* b_in   = (const float*)d_in[3];
    const float* l0_m1w = (const float*)d_in[4];
    const float* l0_m1b = (const float*)d_in[5];
    const float* l0_m2w = (const float*)d_in[6];
    const float* l0_m2b = (const float*)d_in[7];
    const float* l0_u1w = (const float*)d_in[8];
    const float* l0_u1b = (const float*)d_in[9];
    const float* l0_u2w = (const float*)d_in[10];
    const float* l0_u2b = (const float*)d_in[11];
    const float* l1_m1w = (const float*)d_in[12];
    const float* l1_m1b = (const float*)d_in[13];
    const float* l1_m2w = (const float*)d_in[14];
    const float* l1_m2b = (const float*)d_in[15];
    const float* l1_u1w = (const float*)d_in[16];
    const float* l1_u1b = (const float*)d_in[17];
    const float* l1_u2w = (const float*)d_in[18];
    const float* l1_u2b = (const float*)d_in[19];
    const float* h1w    = (const float*)d_in[20];
    const float* h1b    = (const float*)d_in[21];
    const float* h2w    = (const float*)d_in[22];
    const float* h2b    = (const float*)d_in[23];

    float* out = (float*)d_out;

    // workspace layout (aliasing is deliberate, see timeline below)
    float*    h     = (float*)d_ws;                         // N x 64 f32
    float*    agg   = h + (size_t)N_NODES * 64;             // N x 64 f32
    ushort_t* msg16 = (ushort_t*)(agg + (size_t)N_NODES * 64); // N x 64 bf16
    ushort_t* hB16  = msg16 + (size_t)N_NODES * 64;         // N x 64 bf16
    int*      cnt   = (int*)(hB16 + (size_t)N_NODES * 64);  // N
    int*      start = cnt + N_NODES;                        // N + 1
    int*      bsum  = start + N_NODES + 1;                  // NB_SCAN (pad 32)
    int*      curA  = bsum + 32;                            // NBUCK
    int*      csr   = curA + NBUCK;                         // E
    uint2*    pairs = (uint2*)agg;                          // alias: dead before gather writes agg
    ushort_t* hA16  = msg16;                                // alias: msg16 dead after gather1

    const int nodeBlocks = (N_NODES + 255) / 256;
    const int edgeBlocks = (E_EDGES + 255) / 256;
    const int gatherBlocks = (N_NODES + 3) / 4;

    // ---- CSR build (bucket sort: coalesced writes) ----
    hipMemsetAsync(cnt, 0, (size_t)N_NODES * sizeof(int), stream);
    k_hist<<<edgeBlocks, 256, 0, stream>>>(rowIdx, cnt);
    k_bsum<<<NB_SCAN, 256, 0, stream>>>(cnt, bsum);
    k_bscan<<<1, 64, 0, stream>>>(bsum, start);
    k_starts<<<NB_SCAN, 256, 0, stream>>>(cnt, bsum, start);
    k_initcur<<<1, NBUCK, 0, stream>>>(start, curA);
    k_bucketA<<<NBLK_A, 256, 0, stream>>>(rowIdx, colIdx, curA, pairs);
    k_bucketB<<<NBUCK, 256, 0, stream>>>(start, pairs, csr);

    // ---- input linear + layer0 message (fused) ----
    k_lin_msg<<<nodeBlocks, 256, 0, stream>>>(x, w_in, b_in,
                                              l0_m1w, l0_m1b, l0_m2w, l0_m2b, h, msg16);
    // ---- layer 0 aggregate; update + layer1 message (fused) ----
    k_gather<<<gatherBlocks, 256, 0, stream>>>(start, csr, msg16, agg);
    k_update_msg<<<nodeBlocks, 256, 0, stream>>>(h, agg, cnt,
                                                 l0_u1w, l0_u1b, l0_u2w, l0_u2b,
                                                 l1_m1w, l1_m1b, l1_m2w, l1_m2b, msg16);
    // ---- layer 1 aggregate; update + head precompute (fused) ----
    k_gather<<<gatherBlocks, 256, 0, stream>>>(start, csr, msg16, agg);
    k_update_headpre<<<nodeBlocks, 256, 0, stream>>>(h, agg, cnt,
                                                     l1_u1w, l1_u1b, l1_u2w, l1_u2b,
                                                     h1w, h1b, hA16, hB16);
    // ---- head ----
    k_head<<<4096, 256, 0, stream>>>(rowIdx, colIdx, hA16, hB16, h2w, h2b, out);
}